// Round 5
// baseline (249.396 us; speedup 1.0000x reference)
//
#include <hip/hip_runtime.h>
#include <hip/hip_bf16.h>
#include <cstdint>
#include <cstddef>

typedef unsigned short u16;
typedef __bf16 bf16x8 __attribute__((ext_vector_type(8)));
typedef float  f32x4  __attribute__((ext_vector_type(4)));
typedef u16    u16x8  __attribute__((ext_vector_type(8)));
typedef u16    u16x4  __attribute__((ext_vector_type(4)));
typedef short  s16x4  __attribute__((ext_vector_type(4)));

#define MFMA16(A_, B_, C_) __builtin_amdgcn_mfma_f32_16x16x32_bf16((A_), (B_), (C_), 0, 0, 0)
#define MFMA16K16(A_, B_, C_) __builtin_amdgcn_mfma_f32_16x16x16bf16_1k((A_), (B_), (C_), 0, 0, 0)

__device__ __forceinline__ u16 f2bf(float f) {
  return __builtin_bit_cast(u16, (__bf16)f);
}
__device__ __forceinline__ float bf2f(u16 v) {
  return (float)__builtin_bit_cast(__bf16, v);
}

// async global->LDS, 16B per lane. lds must be wave-uniform base; HW adds lane*16.
__device__ __forceinline__ void async16(u16* lds, const u16* g) {
  __builtin_amdgcn_global_load_lds(
      (const __attribute__((address_space(1))) unsigned int*)g,
      (__attribute__((address_space(3))) unsigned int*)lds, 16, 0, 0);
}

// ---------------- prep kernels ----------------

__global__ void cvt_f32_bf16(const float* __restrict__ src, u16* __restrict__ dst, int n4) {
  int i = blockIdx.x * 256 + threadIdx.x;
  if (i < n4) {
    const float4 v = ((const float4*)src)[i];
    u16x4 o;
    o[0] = f2bf(v.x); o[1] = f2bf(v.y); o[2] = f2bf(v.z); o[3] = f2bf(v.w);
    ((u16x4*)dst)[i] = o;
  }
}

__global__ void bn_prep(const float* __restrict__ g, const float* __restrict__ b,
                        const float* __restrict__ rm, const float* __restrict__ rv,
                        float* __restrict__ alpha, float* __restrict__ beta,
                        int n, float scale) {
  int i = blockIdx.x * 256 + threadIdx.x;
  if (i < n) {
    float a0 = g[i] * rsqrtf(rv[i] + 1e-5f);
    alpha[i] = a0 * scale;
    beta[i]  = (b[i] - rm[i] * a0) * scale;
  }
}

// transposed bias table: bias_t[h][k][q]
__global__ void bias_expand_T(const float* __restrict__ attn_bias, const int* __restrict__ idxs,
                              u16* __restrict__ bias_t, int n_off) {
  int i = blockIdx.x * 256 + threadIdx.x;
  if (i < 8 * 1280 * 320) {
    int h = i / (1280 * 320);
    int r = i - h * (1280 * 320);
    int k = r / 320;
    int q = r - k * 320;
    bias_t[i] = f2bf(attn_bias[h * n_off + idxs[q * 1280 + k]]);
  }
}

// ---------------- GEMM 1: kv = x @ W_kv^T, BN, scatter to K / V^T ----------------

__global__ __launch_bounds__(256) void gemm_kv(
    const u16* __restrict__ A, const u16* __restrict__ Wt,
    const float* __restrict__ alpha, const float* __restrict__ beta,
    u16* __restrict__ k_buf, u16* __restrict__ vt_buf) {
  __shared__ __align__(16) u16 As[128 * 64];
  __shared__ __align__(16) u16 Bs[128 * 64];
  const int tid  = threadIdx.x;
  const int lane = tid & 63;
  const int w    = tid >> 6;
  const int wr   = (w >> 1) * 64, wc = (w & 1) * 64;
  const int lr   = lane >> 4, lc = lane & 15;
  const int m0   = blockIdx.x * 128;
  const int n0   = blockIdx.y * 128;
  const int scol  = (lane & 7) * 8;
  f32x4 acc[4][4] = {};

  for (int kt = 0; kt < 256; kt += 64) {
    if (kt) __syncthreads();
#pragma unroll
    for (int i = 0; i < 4; ++i) {
      const int row = w * 32 + i * 8 + (lane >> 3);
      async16(&As[(w * 32 + i * 8) * 64], A  + (size_t)(m0 + row) * 256 + kt + scol);
      async16(&Bs[(w * 32 + i * 8) * 64], Wt + (size_t)(n0 + row) * 256 + kt + scol);
    }
    __syncthreads();
#pragma unroll
    for (int kk = 0; kk < 2; ++kk) {
      bf16x8 af[4], bff[4];
#pragma unroll
      for (int m = 0; m < 4; ++m)
        af[m] = *(const bf16x8*)(&As[(wr + m * 16 + lc) * 64 + kk * 32 + lr * 8]);
#pragma unroll
      for (int n = 0; n < 4; ++n)
        bff[n] = *(const bf16x8*)(&Bs[(wc + n * 16 + lc) * 64 + kk * 32 + lr * 8]);
#pragma unroll
      for (int m = 0; m < 4; ++m)
#pragma unroll
        for (int n = 0; n < 4; ++n)
          acc[m][n] = MFMA16(af[m], bff[n], acc[m][n]);
    }
  }

  const int jr = lr * 4;
#pragma unroll
  for (int m = 0; m < 4; ++m) {
    const int r0  = m0 + wr + m * 16 + jr;
    const int b   = r0 / 1280;
    const int np0 = r0 - b * 1280;
#pragma unroll
    for (int n = 0; n < 4; ++n) {
      const int c    = n0 + wc + n * 16 + lc;
      const float al = alpha[c], be = beta[c];
      const int head = c / 192;
      const int off  = c - head * 192;
      const size_t bh = (size_t)(b * 8 + head);
      if (off < 64) {
#pragma unroll
        for (int j = 0; j < 4; ++j)
          k_buf[(bh * 1280 + np0 + j) * 64 + off] = f2bf(acc[m][n][j] * al + be);
      } else {
        u16x4 pk;
#pragma unroll
        for (int j = 0; j < 4; ++j) pk[j] = f2bf(acc[m][n][j] * al + be);
        *(u16x4*)(&vt_buf[(bh * 128 + (off - 64)) * 1280 + np0]) = pk;
      }
    }
  }
}

// ---------------- GEMM 2: q = subsample(x) @ W_q^T, BN, *0.125 (folded) ----------------

__device__ __forceinline__ int sub_src_row(int qr) {
  if (qr < 256) return ((qr >> 4) * 64) + ((qr & 15) * 2);
  int rr = qr - 256;
  return 1024 + ((rr >> 3) * 32) + ((rr & 7) * 2);
}

__global__ __launch_bounds__(256) void gemm_q(
    const u16* __restrict__ X, const u16* __restrict__ Wt,
    const float* __restrict__ alpha, const float* __restrict__ beta,
    u16* __restrict__ q_buf) {
  __shared__ __align__(16) u16 As[128 * 64];
  __shared__ __align__(16) u16 Bs[128 * 64];
  const int tid  = threadIdx.x;
  const int lane = tid & 63;
  const int w    = tid >> 6;
  const int wr   = (w >> 1) * 64, wc = (w & 1) * 64;
  const int lr   = lane >> 4, lc = lane & 15;
  const int m0   = blockIdx.x * 128;
  const int n0   = blockIdx.y * 128;
  const int scol  = (lane & 7) * 8;
  f32x4 acc[4][4] = {};

  for (int kt = 0; kt < 256; kt += 64) {
    if (kt) __syncthreads();
#pragma unroll
    for (int i = 0; i < 4; ++i) {
      const int row = w * 32 + i * 8 + (lane >> 3);
      const int gr  = m0 + row;
      const int bb  = gr / 320;
      const int qr  = gr - bb * 320;
      async16(&As[(w * 32 + i * 8) * 64],
              X + (size_t)(bb * 1280 + sub_src_row(qr)) * 256 + kt + scol);
      async16(&Bs[(w * 32 + i * 8) * 64], Wt + (size_t)(n0 + row) * 256 + kt + scol);
    }
    __syncthreads();
#pragma unroll
    for (int kk = 0; kk < 2; ++kk) {
      bf16x8 af[4], bff[4];
#pragma unroll
      for (int m = 0; m < 4; ++m)
        af[m] = *(const bf16x8*)(&As[(wr + m * 16 + lc) * 64 + kk * 32 + lr * 8]);
#pragma unroll
      for (int n = 0; n < 4; ++n)
        bff[n] = *(const bf16x8*)(&Bs[(wc + n * 16 + lc) * 64 + kk * 32 + lr * 8]);
#pragma unroll
      for (int m = 0; m < 4; ++m)
#pragma unroll
        for (int n = 0; n < 4; ++n)
          acc[m][n] = MFMA16(af[m], bff[n], acc[m][n]);
    }
  }

  const int jr = lr * 4;
#pragma unroll
  for (int m = 0; m < 4; ++m) {
#pragma unroll
    for (int n = 0; n < 4; ++n) {
      const int c    = n0 + wc + n * 16 + lc;   // < 512
      const float al = alpha[c], be = beta[c];
      const int head = c >> 6, kd = c & 63;
#pragma unroll
      for (int j = 0; j < 4; ++j) {
        const int r  = m0 + wr + m * 16 + jr + j;
        const int b  = r / 320;
        const int qr = r - b * 320;
        q_buf[((size_t)(b * 8 + head) * 320 + qr) * 64 + kd] = f2bf(acc[m][n][j] * al + be);
      }
    }
  }
}

// ---------------- attention ----------------
// Swapped QK^T (mfma(K,Q) -> S^T): lane owns ONE q (=lc), 16 keys in 4-chunks.
// P stays in registers: PV via mfma_16x16x16 (A-frag k-slice == 4-chunk). No P LDS.
// Per-lane scalar m/l; defer-max THR=8 zero-shuffle fast path.
// K/V reg-staged -> XOR-swizzled LDS; T14 prefetch of tile t+1 under compute.

__global__ __launch_bounds__(256) void attn_kernel(
    const u16* __restrict__ q_buf, const u16* __restrict__ k_buf,
    const u16* __restrict__ vt_buf, const u16* __restrict__ bias_t,
    u16* __restrict__ o_buf) {
  __shared__ __align__(16) u16 Ks[64 * 64];    // [key][kd], chunk-swizzled
  __shared__ __align__(16) u16 Vs[128 * 64];   // [d][k-in-tile], chunk-swizzled
  const int tid  = threadIdx.x;
  const int lane = tid & 63;
  const int w    = tid >> 6;
  const int lr   = lane >> 4, lc = lane & 15, jr = lr * 4;
  // XCD swizzle: co-locate the 5 q-tiles of each (b,h) on one XCD
  const int g   = blockIdx.x;
  const int f   = (g & 7) * 160 + (g >> 3);
  const int qt  = f % 5;
  const int bh_ = f / 5;
  const int h = bh_ & 7, b = bh_ >> 3;
  const size_t bh = (size_t)bh_;
  const int q0 = qt * 64 + w * 16;
  const int swzk = (lc & 7) << 4;

  bf16x8 bq0, bq1;  // Q as B-operand (same fragment layout as A)
  {
    const u16* qp = q_buf + (bh * 320 + q0 + lc) * 64 + lr * 8;
    bq0 = *(const bf16x8*)(qp);
    bq1 = *(const bf16x8*)(qp + 32);
  }

  f32x4 oacc[8] = {};
  float mrun = -3e38f;
  float lacc = 0.f;

  const u16* bias_base = bias_t + (size_t)h * 1280 * 320 + q0 + lc;

  // staging registers (tile t+1 in flight during compute of t)
  u16x8 kreg[2], vreg[4];
  u16 bbA[16], bbB[16];
  const int srow = tid >> 3, sch = tid & 7;

  auto gkv = [&](int kt) {
    const u16* kg = k_buf + bh * 81920 + (size_t)(kt * 64 + srow) * 64 + sch * 8;
    kreg[0] = *(const u16x8*)(kg);
    kreg[1] = *(const u16x8*)(kg + 32 * 64);
    const u16* vg = vt_buf + bh * 163840 + (size_t)srow * 1280 + kt * 64 + sch * 8;
#pragma unroll
    for (int i = 0; i < 4; ++i) vreg[i] = *(const u16x8*)(vg + (size_t)i * 32 * 1280);
  };
  auto gbias = [&](int kt, u16* dst) {
    const u16* bp = bias_base + (size_t)(kt * 64 + lr * 4) * 320;
#pragma unroll
    for (int n = 0; n < 4; ++n)
#pragma unroll
      for (int j = 0; j < 4; ++j)
        dst[n * 4 + j] = bp[(size_t)(n * 16 + j) * 320];
  };
  auto swzw = [&](u16* base, int row, int c, u16x8 v) {
    *(u16x8*)((char*)base + row * 128 + ((c * 16) ^ ((row & 7) << 4)));
    *(u16x8*)((char*)base + row * 128 + ((c * 16) ^ ((row & 7) << 4))) = v;
  };

  auto step = [&](int kt, const u16* bb, u16* bbn) {
    __syncthreads();                       // prior tile's LDS reads complete
    swzw(Ks, srow, sch, kreg[0]);
    swzw(Ks, srow + 32, sch, kreg[1]);
#pragma unroll
    for (int i = 0; i < 4; ++i) swzw(Vs, srow + i * 32, sch, vreg[i]);
    __syncthreads();
    const int ktn = (kt < 19) ? kt + 1 : 19;
    gkv(ktn);                              // fire next-tile loads (T14)
    gbias(ktn, bbn);

    // S^T = K Q^T : pv[n][j] = S[q=lc][key = n*16 + lr*4 + j]
    float pv[4][4];
    __builtin_amdgcn_s_setprio(1);
#pragma unroll
    for (int n = 0; n < 4; ++n) {
      const char* kp = (const char*)&Ks[(n * 16 + lc) * 64];
      f32x4 t = {};
      t = MFMA16(*(const bf16x8*)(kp + ((lr * 16) ^ swzk)), bq0, t);
      t = MFMA16(*(const bf16x8*)(kp + ((64 + lr * 16) ^ swzk)), bq1, t);
#pragma unroll
      for (int j = 0; j < 4; ++j) pv[n][j] = t[j] + bf2f(bb[n * 4 + j]);
    }
    __builtin_amdgcn_s_setprio(0);

    // per-lane max over this lane's 16 keys
    float mx = pv[0][0];
#pragma unroll
    for (int n = 0; n < 4; ++n)
#pragma unroll
      for (int j = 0; j < 4; ++j) mx = fmaxf(mx, pv[n][j]);

    if (!__all(mx <= mrun + 8.f)) {
      float v = fmaxf(mx, __shfl_xor(mx, 16));
      v = fmaxf(v, __shfl_xor(v, 32));     // row max, uniform across lr
      const float mnew = fmaxf(mrun, v);
      const float corr = __expf(mrun - mnew);
      mrun = mnew;
      lacc *= corr;
      // oacc rows are q = jr+j: fetch corr for those q (lanes 0..15 hold q=lc)
      float cq[4];
#pragma unroll
      for (int j = 0; j < 4; ++j) cq[j] = __shfl(corr, jr + j);
#pragma unroll
      for (int nc = 0; nc < 8; ++nc)
#pragma unroll
        for (int j = 0; j < 4; ++j) oacc[nc][j] *= cq[j];
    }

    // exp, in-lane row-sum, pack to bf16 A-frags for K=16 PV
    s16x4 pa[4];
    float s = 0.f;
#pragma unroll
    for (int n = 0; n < 4; ++n) {
      u16x4 pk;
#pragma unroll
      for (int j = 0; j < 4; ++j) {
        const float e = __expf(pv[n][j] - mrun);
        s += e;
        pk[j] = f2bf(e);
      }
      pa[n] = __builtin_bit_cast(s16x4, pk);
    }
    lacc += s;

    // PV: O[q][d] += P[q][k] V[k][d], 4 x K=16 mfma per 16-wide d block
    __builtin_amdgcn_s_setprio(1);
#pragma unroll
    for (int nc = 0; nc < 8; ++nc) {
      const int drow = nc * 16 + lc;
      const char* vrow = (const char*)Vs + drow * 128;
#pragma unroll
      for (int t = 0; t < 4; ++t) {
        const int chunk = ((t * 2 + (lr >> 1)) ^ (drow & 7));
        const s16x4 vf = __builtin_bit_cast(
            s16x4, *(const u16x4*)(vrow + chunk * 16 + (lr & 1) * 8));
        oacc[nc] = MFMA16K16(pa[t], vf, oacc[nc]);
      }
    }
    __builtin_amdgcn_s_setprio(0);
  };

  gkv(0);
  gbias(0, bbA);
#pragma unroll 1
  for (int kt = 0; kt < 20; kt += 2) {
    step(kt, bbA, bbB);
    step(kt + 1, bbB, bbA);
  }

  // reduce l across lr groups, then transpose to q = jr+j
  lacc += __shfl_xor(lacc, 16);
  lacc += __shfl_xor(lacc, 32);
  float invl[4];
#pragma unroll
  for (int j = 0; j < 4; ++j) invl[j] = 1.f / __shfl(lacc, jr + j);

#pragma unroll
  for (int nc = 0; nc < 8; ++nc) {
#pragma unroll
    for (int j = 0; j < 4; ++j) {
      const float xv = oacc[nc][j] * invl[j];
      const float hs = xv * fminf(fmaxf(xv + 3.f, 0.f), 6.f) * (1.f / 6.f);
      o_buf[((size_t)b * 320 + q0 + jr + j) * 1024 + h * 128 + nc * 16 + lc] = f2bf(hs);
    }
  }
}

// ---------------- GEMM 3: out = hswish(o) @ W_p^T, BN (f32 out) ----------------

__global__ __launch_bounds__(256) void gemm_p(
    const u16* __restrict__ O, const u16* __restrict__ Wt,
    const float* __restrict__ alpha, const float* __restrict__ beta,
    float* __restrict__ out) {
  __shared__ __align__(16) u16 As[128 * 64];
  __shared__ __align__(16) u16 Bs[128 * 64];
  const int tid  = threadIdx.x;
  const int lane = tid & 63;
  const int w    = tid >> 6;
  const int wr   = (w >> 1) * 64, wc = (w & 1) * 64;
  const int lr   = lane >> 4, lc = lane & 15;
  const int m0   = blockIdx.x * 128;
  const int n0   = blockIdx.y * 128;
  const int scol  = (lane & 7) * 8;
  f32x4 acc[4][4] = {};

  for (int kt = 0; kt < 1024; kt += 64) {
    if (kt) __syncthreads();
#pragma unroll
    for (int i = 0; i < 4; ++i) {
      const int row = w * 32 + i * 8 + (lane >> 3);
      async16(&As[(w * 32 + i * 8) * 64], O  + (size_t)(m0 + row) * 1024 + kt + scol);
      async16(&Bs[(w * 32 + i * 8) * 64], Wt + (size_t)(n0 + row) * 1024 + kt + scol);
    }
    __syncthreads();
#pragma unroll
    for (int kk = 0; kk < 2; ++kk) {
      bf16x8 af[4], bff[4];
#pragma unroll
      for (int m = 0; m < 4; ++m)
        af[m] = *(const bf16x8*)(&As[(wr + m * 16 + lc) * 64 + kk * 32 + lr * 8]);
#pragma unroll
      for (int n = 0; n < 4; ++n)
        bff[n] = *(const bf16x8*)(&Bs[(wc + n * 16 + lc) * 64 + kk * 32 + lr * 8]);
#pragma unroll
      for (int m = 0; m < 4; ++m)
#pragma unroll
        for (int n = 0; n < 4; ++n)
          acc[m][n] = MFMA16(af[m], bff[n], acc[m][n]);
    }
  }

  const int jr = lr * 4;
#pragma unroll
  for (int m = 0; m < 4; ++m) {
#pragma unroll
    for (int n = 0; n < 4; ++n) {
      const int c = n0 + wc + n * 16 + lc;   // < 384
      const float al = alpha[c], be = beta[c];
#pragma unroll
      for (int j = 0; j < 4; ++j) {
        const int r = m0 + wr + m * 16 + jr + j;
        out[(size_t)r * 384 + c] = acc[m][n][j] * al + be;
      }
    }
  }
}

// ---------------- launch ----------------

extern "C" void kernel_launch(void* const* d_in, const int* in_sizes, int n_in,
                              void* d_out, int out_size, void* d_ws, size_t ws_size,
                              hipStream_t stream) {
  const float* x      = (const float*)d_in[0];
  const float* W_kv   = (const float*)d_in[1];
  const float* g_kv   = (const float*)d_in[2];
  const float* b_kv   = (const float*)d_in[3];
  const float* rm_kv  = (const float*)d_in[4];
  const float* rv_kv  = (const float*)d_in[5];
  const float* W_q    = (const float*)d_in[6];
  const float* g_q    = (const float*)d_in[7];
  const float* b_q    = (const float*)d_in[8];
  const float* rm_q   = (const float*)d_in[9];
  const float* rv_q   = (const float*)d_in[10];
  const float* W_p    = (const float*)d_in[11];
  const float* g_p    = (const float*)d_in[12];
  const float* b_p    = (const float*)d_in[13];
  const float* rm_p   = (const float*)d_in[14];
  const float* rv_p   = (const float*)d_in[15];
  const float* attn_bias = (const float*)d_in[16];
  const int*   bias_idxs = (const int*)d_in[17];
  const int n_off = in_sizes[16] / 8;

  char* ws = (char*)d_ws;
  size_t off = 0;
  auto alloc = [&](size_t bytes) -> void* {
    void* p = ws + off;
    off += (bytes + 255) & ~(size_t)255;
    return p;
  };
  u16* x_bf    = (u16*)alloc((size_t)40960 * 256 * 2);
  u16* wkv_bf  = (u16*)alloc((size_t)1536 * 256 * 2);
  u16* wq_bf   = (u16*)alloc((size_t)512 * 256 * 2);
  u16* wp_bf   = (u16*)alloc((size_t)384 * 1024 * 2);
  float* al_kv = (float*)alloc(1536 * 4);
  float* be_kv = (float*)alloc(1536 * 4);
  float* al_q  = (float*)alloc(512 * 4);
  float* be_q  = (float*)alloc(512 * 4);
  float* al_p  = (float*)alloc(384 * 4);
  float* be_p  = (float*)alloc(384 * 4);
  u16* k_buf   = (u16*)alloc((size_t)32 * 8 * 1280 * 64 * 2);
  u16* vt_buf  = (u16*)alloc((size_t)32 * 8 * 128 * 1280 * 2);
  u16* q_buf   = (u16*)alloc((size_t)32 * 8 * 320 * 64 * 2);
  u16* bias_t  = (u16*)alloc((size_t)8 * 1280 * 320 * 2);
  u16* o_buf   = (u16*)alloc((size_t)32 * 320 * 1024 * 2);
  (void)ws_size; (void)n_in; (void)out_size;

  cvt_f32_bf16<<<(2621440 + 255) / 256, 256, 0, stream>>>(x, x_bf, 2621440);
  cvt_f32_bf16<<<(98304 + 255) / 256, 256, 0, stream>>>(W_kv, wkv_bf, 98304);
  cvt_f32_bf16<<<(32768 + 255) / 256, 256, 0, stream>>>(W_q, wq_bf, 32768);
  cvt_f32_bf16<<<(98304 + 255) / 256, 256, 0, stream>>>(W_p, wp_bf, 98304);
  bn_prep<<<6, 256, 0, stream>>>(g_kv, b_kv, rm_kv, rv_kv, al_kv, be_kv, 1536, 1.0f);
  bn_prep<<<2, 256, 0, stream>>>(g_q, b_q, rm_q, rv_q, al_q, be_q, 512, 0.125f);
  bn_prep<<<2, 256, 0, stream>>>(g_p, b_p, rm_p, rv_p, al_p, be_p, 384, 1.0f);
  bias_expand_T<<<(3276800 + 255) / 256, 256, 0, stream>>>(attn_bias, bias_idxs, bias_t, n_off);

  gemm_kv<<<dim3(320, 12), 256, 0, stream>>>(x_bf, wkv_bf, al_kv, be_kv, k_buf, vt_buf);
  gemm_q<<<dim3(80, 4), 256, 0, stream>>>(x_bf, wq_bf, al_q, be_q, q_buf);
  attn_kernel<<<dim3(1280), 256, 0, stream>>>(q_buf, k_buf, vt_buf, bias_t, o_buf);
  gemm_p<<<dim3(80, 3), 256, 0, stream>>>(o_buf, wp_bf, al_p, be_p, (float*)d_out);
}